// Round 8
// baseline (1752.494 us; speedup 1.0000x reference)
//
#include <hip/hip_runtime.h>
#include <math.h>

#define BATCH 16
#define CDIM 256
#define NCLS 80
#define N3 16384
#define N4 4096
#define N5 1024
#define NTOK 21504
#define KQ 300
#define KSEL 512
#define CANDMAX 1024
#define HBIN 2048
#define KMIN 0x3E800000u   // fp32 bits of 0.25

typedef __attribute__((ext_vector_type(8))) short short8;
typedef __attribute__((ext_vector_type(4))) float floatx4;
typedef unsigned short ushort_t;

// ldsA address (u16 units): [tok][264], 16B-chunk XOR-swizzled by tok&7.
#define LA(tok, k) (((tok) * 264) + (((((k) >> 3) ^ ((tok) & 7)) << 3) | ((k) & 7)))

__device__ __forceinline__ float sigmoidf_(float x) {
    return 1.0f / (1.0f + __expf(-x));
}

__device__ __forceinline__ ushort_t f2bf(float f) {   // RNE f32->bf16
    unsigned int x = __float_as_uint(f);
    unsigned int r = (x + 0x7FFFu + ((x >> 16) & 1u)) >> 16;
    return (ushort_t)r;
}

__device__ __forceinline__ void gload16(const void* g, void* l) {
    __builtin_amdgcn_global_load_lds(
        (const __attribute__((address_space(1))) unsigned int*)g,
        (__attribute__((address_space(3))) unsigned int*)l,
        16, 0, 0);
}

__device__ __forceinline__ void locate_level(
    int n, int bb,
    const float* __restrict__ s3, const float* __restrict__ s4, const float* __restrict__ s5,
    const float*& src, int& nloc, int& lsz)
{
    if (n < N3)           { src = s3 + (size_t)bb * CDIM * N3; nloc = n;           lsz = N3; }
    else if (n < N3 + N4) { src = s4 + (size_t)bb * CDIM * N4; nloc = n - N3;      lsz = N4; }
    else                  { src = s5 + (size_t)bb * CDIM * N5; nloc = n - N3 - N4; lsz = N5; }
}

// -------- Kernel 0: transpose+cast weights to bf16 W^T[col][k], PRE-SWIZZLED --------
__global__ __launch_bounds__(256) void prep_weights(
    const float* __restrict__ w1, const float* __restrict__ w2,
    const float* __restrict__ w_score,
    ushort_t* __restrict__ w1T, ushort_t* __restrict__ w2T, ushort_t* __restrict__ wsT)
{
    const int k = threadIdx.x;
    const int c = blockIdx.x;
    const int klo = k & 7;
    if (c < 256) {
        const size_t d = (size_t)c * 256 + ((((k >> 3) ^ (c & 7)) << 3) | klo);
        w1T[d] = f2bf(w1[k * 256 + c]);
    } else if (c < 512) {
        const int c2 = c - 256;
        const size_t d = (size_t)c2 * 256 + ((((k >> 3) ^ (c2 & 7)) << 3) | klo);
        w2T[d] = f2bf(w2[k * 256 + c2]);
    } else {
        const int c2 = c - 512;
        const size_t d = (size_t)c2 * 256 + ((((k >> 3) ^ (c2 & 7)) << 3) | klo);
        wsT[d] = (c2 < NCLS) ? f2bf(w_score[k * NCLS + c2]) : (ushort_t)0;
    }
}

// -------- Kernel 1: fused encoder head, 38-step counted-vmcnt pipeline (T4+T5) --------
// grid: BATCH*336 blocks (64 tokens), 256 threads = 4 waves.
// Steps: (colblock cb = i>>1, k-half h = i&1); 8KB weight half-chunks, wbufL[3].
// DMA for step i+2 issued LAST in step i (newest 2 vmem ops); end-of-step sync is
// "s_waitcnt vmcnt(2) lgkmcnt(0); s_barrier" -> step i+1's loads drained, step
// i+2's stay in flight across the barrier (never drain to 0 in the loop).
__global__ __launch_bounds__(256, 2) void enc_mfma_kernel(
    const float* __restrict__ s3, const float* __restrict__ s4, const float* __restrict__ s5,
    const ushort_t* __restrict__ w1T, const ushort_t* __restrict__ w2T,
    const ushort_t* __restrict__ wsT,
    const float* __restrict__ b_score, const float* __restrict__ b1,
    const float* __restrict__ b2,
    const float* __restrict__ w3, const float* __restrict__ b3,
    float* __restrict__ out_logits, float* __restrict__ out_sboxes,
    float* __restrict__ ws_scores)
{
    __shared__ __align__(16) ushort_t ldsA[64 * 264];       // 33792 B: memB then h1
    __shared__ __align__(16) ushort_t wbufL[3][32 * 128];   // 3 x 8192 B (linear DMA dest)
    __shared__ float bsc_s[80];
    __shared__ float b1_s[256];
    __shared__ float b2_s[256];
    __shared__ __align__(16) float w3_s[256 * 4];
    __shared__ float smax_s[2][64];
    __shared__ __align__(16) float boxp[2][64][4];

    const int t = threadIdx.x;
    const int lane = t & 63;
    const int w = t >> 6;
    const int tw = w & 1;                 // token half: tiles {32tw, 32tw+16}
    const int cw = w >> 1;                // col half within each 32-col chunk
    const int ml = lane & 15;
    const int quad = lane >> 4;
    const int kq = quad * 8;
    const int m8 = ml & 7;

    const int bb = blockIdx.x / 336;
    const int tile_ = blockIdx.x % 336;
    const int T0 = tile_ * 64;

    // stage one 32col x 128k half-chunk (8 KB). Packed layout: per col 512 B row,
    // k-half h occupies swizzled-chunk range [16h,16h+16) = bytes [h*256, h*256+256).
    // Per-lane global addr + wave-uniform-base+lane*16 LDS dest (2 gload16/thread).
    auto stage_half = [&](const ushort_t* wg, int h, int dbuf) {
        const char* gb = (const char*)wg + h * 256;
        char* l = (char*)&wbufL[dbuf][0];
        #pragma unroll
        for (int ii = 0; ii < 2; ++ii) {
            const int u = t + 256 * ii;                  // 0..511
            gload16(gb + (u >> 4) * 512 + (u & 15) * 16, l + u * 16);
        }
    };

    stage_half(wsT, 0, 0);                // step 0 DMA in flight during staging

    if (t < 80) bsc_s[t] = b_score[t];
    b1_s[t] = b1[t];
    b2_s[t] = b2[t];
    *(float4*)&w3_s[t * 4] = *(const float4*)(w3 + t * 4);

    const float* src; int nloc, lsz;
    locate_level(T0, bb, s3, s4, s5, src, nloc, lsz);

    // ---- stage memory tile TRANSPOSED: [k][tok] global -> [tok][k] LDS (swizzled) ----
    {
        const int tokq = t & 15;          // owns toks 4*tokq .. +3
        const int kg = t >> 4;            // 16 k-groups of 8
        #pragma unroll
        for (int p = 0; p < 2; ++p) {
            const int kbase = 8 * kg + 128 * p;
            float4 v[8];
            #pragma unroll
            for (int j = 0; j < 8; ++j)
                v[j] = *(const float4*)(src + (size_t)(kbase + j) * lsz + nloc + 4 * tokq);
            #pragma unroll
            for (int r = 0; r < 4; ++r) {
                short8 a;
                #pragma unroll
                for (int j = 0; j < 8; ++j)
                    a[j] = (short)f2bf(((const float*)&v[j])[r]);
                *(short8*)&ldsA[LA(4 * tokq + r, kbase)] = a;
            }
        }
    }

    __builtin_amdgcn_sched_barrier(0);
    stage_half(wsT, 1, 1);                // step 1 DMA (issued late: newest 2 ops)
    // drain step 0 (keep step 1 in flight), make tile ds_writes visible
    asm volatile("s_waitcnt vmcnt(2) lgkmcnt(0)\ns_barrier" ::: "memory");

    // ---- A1 fragments: 16 x ds_read_b128 (row=tok=32tw+16tl+ml, k=32f+kq..+8) ----
    short8 af[2][8];
    #pragma unroll
    for (int tl = 0; tl < 2; ++tl) {
        const int tok = 32 * tw + 16 * tl + ml;
        #pragma unroll
        for (int f = 0; f < 8; ++f)
            af[tl][f] = *(const short8*)&ldsA[LA(tok, 32 * f + kq)];
    }

    const int gtok0 = bb * NTOK + T0;

    float smaxr[2][4];
    #pragma unroll
    for (int tl = 0; tl < 2; ++tl)
        #pragma unroll
        for (int r = 0; r < 4; ++r) smaxr[tl][r] = -1e30f;

    float psum[2][4][4];
    #pragma unroll
    for (int tl = 0; tl < 2; ++tl)
        #pragma unroll
        for (int r = 0; r < 4; ++r)
            #pragma unroll
            for (int c = 0; c < 4; ++c) psum[tl][r][c] = 0.f;

    floatx4 acc0 = {0.f, 0.f, 0.f, 0.f};
    floatx4 acc1 = {0.f, 0.f, 0.f, 0.f};
    const int brow = (16 * cw + ml) * 128;

    for (int i = 0; i < 38; ++i) {
        const int cb = i >> 1;            // colblock 0..18
        const int h = i & 1;              // k-half

        // A2 fragments from h1 (complete as of barrier at end of step 21)
        if (i == 22) {
            #pragma unroll
            for (int tl = 0; tl < 2; ++tl) {
                const int tok = 32 * tw + 16 * tl + ml;
                #pragma unroll
                for (int f = 0; f < 8; ++f)
                    af[tl][f] = *(const short8*)&ldsA[LA(tok, 32 * f + kq)];
            }
        }

        if (h == 0) {
            acc0 = (floatx4){0.f, 0.f, 0.f, 0.f};
            acc1 = (floatx4){0.f, 0.f, 0.f, 0.f};
        }

        const ushort_t* wb = &wbufL[i % 3][0];
        __builtin_amdgcn_s_setprio(1);
        #pragma unroll
        for (int f2 = 0; f2 < 4; ++f2) {
            const short8 bf = *(const short8*)&wb[brow + ((((4 * f2 + quad) ^ m8)) << 3)];
            acc0 = __builtin_amdgcn_mfma_f32_16x16x32_bf16(af[0][4 * h + f2], bf, acc0, 0, 0, 0);
            acc1 = __builtin_amdgcn_mfma_f32_16x16x32_bf16(af[1][4 * h + f2], bf, acc1, 0, 0, 0);
        }
        __builtin_amdgcn_s_setprio(0);

        if (h == 1) {
            if (cb < 3) {
                // GEMM1: logits + running row max
                const int col = 32 * cb + 16 * cw + ml;
                if (col < NCLS) {         // wave-uniform per (cb,cw)
                    const float bias = bsc_s[col];
                    #pragma unroll
                    for (int tl = 0; tl < 2; ++tl)
                        #pragma unroll
                        for (int r = 0; r < 4; ++r) {
                            const float v = (tl ? acc1[r] : acc0[r]) + bias;
                            const int ltok = 32 * tw + 16 * tl + 4 * quad + r;
                            out_logits[(size_t)(gtok0 + ltok) * NCLS + col] = v;
                            smaxr[tl][r] = fmaxf(smaxr[tl][r], v);
                        }
                }
                if (i == 5) {             // GEMM1 done: reduce over 16 col-lanes
                    #pragma unroll
                    for (int tl = 0; tl < 2; ++tl)
                        #pragma unroll
                        for (int r = 0; r < 4; ++r) {
                            float m = smaxr[tl][r];
                            m = fmaxf(m, __shfl_xor(m, 1));
                            m = fmaxf(m, __shfl_xor(m, 2));
                            m = fmaxf(m, __shfl_xor(m, 4));
                            m = fmaxf(m, __shfl_xor(m, 8));
                            if (ml == 0)
                                smax_s[cw][32 * tw + 16 * tl + 4 * quad + r] = m;
                        }
                }
            } else if (cb < 11) {
                // GEMM2: h1 = relu(.) -> ldsA (A1 already in regs)
                const int col = 32 * (cb - 3) + 16 * cw + ml;
                const float bias = b1_s[col];
                #pragma unroll
                for (int tl = 0; tl < 2; ++tl)
                    #pragma unroll
                    for (int r = 0; r < 4; ++r) {
                        const float v = fmaxf((tl ? acc1[r] : acc0[r]) + bias, 0.f);
                        const int ltok = 32 * tw + 16 * tl + 4 * quad + r;
                        ldsA[LA(ltok, col)] = f2bf(v);
                    }
            } else {
                // GEMM3: h2 = relu(.); boxes folded in-register
                const int col = 32 * (cb - 11) + 16 * cw + ml;
                const float bias = b2_s[col];
                const float4 w3v = *(const float4*)&w3_s[col * 4];
                #pragma unroll
                for (int tl = 0; tl < 2; ++tl)
                    #pragma unroll
                    for (int r = 0; r < 4; ++r) {
                        const float v = fmaxf((tl ? acc1[r] : acc0[r]) + bias, 0.f);
                        psum[tl][r][0] = fmaf(v, w3v.x, psum[tl][r][0]);
                        psum[tl][r][1] = fmaf(v, w3v.y, psum[tl][r][1]);
                        psum[tl][r][2] = fmaf(v, w3v.z, psum[tl][r][2]);
                        psum[tl][r][3] = fmaf(v, w3v.w, psum[tl][r][3]);
                    }
            }
        }

        // issue step i+2's DMA LAST (newest 2 vmem ops), then counted-wait barrier
        __builtin_amdgcn_sched_barrier(0);
        if (i + 2 < 38) {
            const int j = i + 2;
            const int jc = j >> 1, jh = j & 1;
            const ushort_t* nxt = (jc < 3)  ? (wsT + (size_t)jc * 8192)
                                : (jc < 11) ? (w1T + (size_t)(jc - 3) * 8192)
                                            : (w2T + (size_t)(jc - 11) * 8192);
            stage_half(nxt, jh, j % 3);
            asm volatile("s_waitcnt vmcnt(2) lgkmcnt(0)\ns_barrier" ::: "memory");
        } else {
            asm volatile("s_waitcnt vmcnt(0) lgkmcnt(0)\ns_barrier" ::: "memory");
        }
    }

    // ---- boxes: reduce psum over 16 col-lanes, cross-wave (cw) combine via LDS ----
    #pragma unroll
    for (int tl = 0; tl < 2; ++tl)
        #pragma unroll
        for (int r = 0; r < 4; ++r) {
            float4 pv;
            float* pva = (float*)&pv;
            #pragma unroll
            for (int c = 0; c < 4; ++c) {
                float v = psum[tl][r][c];
                v += __shfl_xor(v, 1);
                v += __shfl_xor(v, 2);
                v += __shfl_xor(v, 4);
                v += __shfl_xor(v, 8);
                pva[c] = v;
            }
            if (ml == 0)
                *(float4*)&boxp[cw][32 * tw + 16 * tl + 4 * quad + r][0] = pv;
        }
    __syncthreads();

    if (t < 64)
        ws_scores[gtok0 + t] = sigmoidf_(fmaxf(smax_s[0][t], smax_s[1][t]));
    {
        const int tok = t >> 2, c = t & 3;
        const float bx = boxp[0][tok][c] + boxp[1][tok][c] + b3[c];
        out_sboxes[(size_t)(gtok0 + tok) * 4 + c] = sigmoidf_(bx);
    }
}

// -------- select stage A: zero hist + cand_cnt --------
__global__ __launch_bounds__(256) void zero_sel(
    unsigned int* __restrict__ hist, unsigned int* __restrict__ cand_cnt)
{
    const int idx = blockIdx.x * 256 + threadIdx.x;
    for (int i = idx; i < BATCH * HBIN; i += 32 * 256) hist[i] = 0u;
    if (idx < BATCH) cand_cnt[idx] = 0u;
}

// -------- select stage B: 256-block histogram over 2048 value-bins of [0.25,1) --------
__global__ __launch_bounds__(256) void hist_sel(
    const float* __restrict__ scores, unsigned int* __restrict__ hist)
{
    __shared__ unsigned int lhist[HBIN];
    const int t = threadIdx.x;
    const int bb = blockIdx.x >> 4;
    const int slice = blockIdx.x & 15;
    const float* s = scores + bb * NTOK;
    #pragma unroll
    for (int j = 0; j < HBIN / 256; ++j) lhist[t + 256 * j] = 0u;
    __syncthreads();

    const int base = slice * (NTOK / 16);
    for (int n = base + t; n < base + NTOK / 16; n += 256) {
        const unsigned int key = __float_as_uint(s[n]);
        int b;
        if (key < KMIN) b = 0;
        else {
            unsigned int d = (key - KMIN) >> 13;
            b = (d > (unsigned int)(HBIN - 1)) ? (HBIN - 1) : (int)d;
        }
        atomicAdd(&lhist[b], 1u);
    }
    __syncthreads();
    #pragma unroll
    for (int j = 0; j < HBIN / 256; ++j) {
        const unsigned int v = lhist[t + 256 * j];
        if (v) atomicAdd(&hist[bb * HBIN + t + 256 * j], v);
    }
}

// -------- select stage C: scan hist, pick threshold key (suffix >= KSEL) --------
__global__ __launch_bounds__(256) void scan_sel(
    const unsigned int* __restrict__ hist, unsigned int* __restrict__ tkeyArr)
{
    __shared__ unsigned int part[256];
    const int bb = blockIdx.x;
    const int t = threadIdx.x;
    unsigned int s = 0;
    #pragma unroll
    for (int j = 0; j < 8; ++j) s += hist[bb * HBIN + t * 8 + j];
    part[t] = s;
    __syncthreads();
    if (t == 0) {
        int acc = 0, g = 255;
        for (; g >= 0; --g) {
            if (acc + (int)part[g] >= KSEL) break;
            acc += (int)part[g];
        }
        unsigned int key;
        if (g < 0) {
            key = 1u;                      // degenerate: take all positive scores
        } else {
            int b = 8 * g + 7;
            for (; b > 8 * g; --b) {
                acc += (int)hist[bb * HBIN + b];
                if (acc >= KSEL) break;
            }
            if (acc < KSEL) { acc += (int)hist[bb * HBIN + 8 * g]; b = 8 * g; }
            key = (b == 0) ? 1u : (KMIN + ((unsigned int)b << 13));
        }
        tkeyArr[bb] = key;
    }
}

// -------- select stage D: parallel ballot-collect of all tokens >= Tkey --------
__global__ __launch_bounds__(256) void collect_sel(
    const float* __restrict__ scores, const unsigned int* __restrict__ tkeyArr,
    int* __restrict__ cand_idx, unsigned int* __restrict__ cand_cnt)
{
    const int t = threadIdx.x;
    const int lane = t & 63;
    const int bb = blockIdx.x >> 4;
    const int slice = blockIdx.x & 15;
    const float* s = scores + bb * NTOK;
    const unsigned int Tkey = tkeyArr[bb];

    const int base = slice * (NTOK / 16);
    for (int n = base + t; n < base + NTOK / 16; n += 256) {
        const unsigned int key = __float_as_uint(s[n]);
        const bool pred = (key >= Tkey);
        const unsigned long long m = __ballot(pred);
        if (m) {
            const int leader = __builtin_ctzll(m);
            unsigned int bpos = 0;
            if (lane == leader)
                bpos = atomicAdd(&cand_cnt[bb], (unsigned int)__popcll(m));
            bpos = (unsigned int)__shfl((int)bpos, leader);
            if (pred) {
                const unsigned int pos =
                    bpos + (unsigned int)__popcll(m & ((1ull << lane) - 1ull));
                if (pos < CANDMAX) cand_idx[bb * CANDMAX + pos] = n;
            }
        }
    }
}

// -------- Kernel 3: f64 exact rescore, one block per candidate --------
__global__ __launch_bounds__(256) void rescore_kernel(
    const float* __restrict__ s3, const float* __restrict__ s4, const float* __restrict__ s5,
    const float* __restrict__ w_score, const float* __restrict__ b_score,
    const int* __restrict__ cand_idx, const unsigned int* __restrict__ cand_cnt,
    double* __restrict__ cand_score, float* __restrict__ cand_mem, int use_cmem)
{
    __shared__ float m_s[CDIM];
    __shared__ double part[256];

    const int t = threadIdx.x;
    const int bb = blockIdx.x / CANDMAX;
    const int cpos = blockIdx.x % CANDMAX;
    if ((unsigned int)cpos >= cand_cnt[bb]) return;

    const int n = cand_idx[bb * CANDMAX + cpos];
    const float* src; int nloc, lsz;
    locate_level(n, bb, s3, s4, s5, src, nloc, lsz);
    m_s[t] = src[(size_t)t * lsz + nloc];
    __syncthreads();

    if (use_cmem)
        cand_mem[((size_t)bb * CANDMAX + cpos) * CDIM + t] = m_s[t];

    const int ks = t >> 7;
    const int c = t & 127;
    double acc = 0.0;
    if (c < NCLS) {
        if (ks == 0) acc = (double)b_score[c];
        const int k0 = 128 * ks;
        for (int k = k0; k < k0 + 128; ++k)
            acc += (double)m_s[k] * (double)w_score[k * NCLS + c];
    }
    part[t] = acc;
    __syncthreads();

    if (t < 128) {
        double tot = (t < NCLS) ? (part[t] + part[t + 128]) : -1.0e300;
        part[t] = tot;
    }
    __syncthreads();

    if (t < 64) {
        double v = fmax(part[t], part[t + 64]);
        v = fmax(v, __shfl_xor(v, 1));
        v = fmax(v, __shfl_xor(v, 2));
        v = fmax(v, __shfl_xor(v, 4));
        v = fmax(v, __shfl_xor(v, 8));
        v = fmax(v, __shfl_xor(v, 16));
        v = fmax(v, __shfl_xor(v, 32));
        if (t == 0) cand_score[bb * CANDMAX + cpos] = v;
    }
}

// -------- Kernel 4: exact sort of candidates, emit top-300 (+cand position) --------
__global__ __launch_bounds__(512) void fsort_kernel(
    const double* __restrict__ cand_score, const int* __restrict__ cand_idx,
    const unsigned int* __restrict__ cand_cnt,
    float* __restrict__ out_idx_f, float* __restrict__ out_scores,
    int* __restrict__ ws_idx, int* __restrict__ ws_pos)
{
    __shared__ double ss[CANDMAX];
    __shared__ int    ii[CANDMAX];
    __shared__ int    pp[CANDMAX];
    const int bb = blockIdx.x;
    const int t = threadIdx.x;
    const unsigned int cnt = cand_cnt[bb];

    for (int i = t; i < CANDMAX; i += 512) {
        if ((unsigned int)i < cnt) {
            ss[i] = cand_score[bb * CANDMAX + i];
            ii[i] = cand_idx[bb * CANDMAX + i];
        } else {
            ss[i] = -1.0e300;
            ii[i] = 0x7FFFFFFF;
        }
        pp[i] = i;
    }
    __syncthreads();

    for (int ksz = 2; ksz <= CANDMAX; ksz <<= 1) {
        for (int j = ksz >> 1; j > 0; j >>= 1) {
            #pragma unroll
            for (int p = 0; p < CANDMAX / 512; p++) {
                const int i = p * 512 + t;
                const int ixj = i ^ j;
                if (ixj > i) {
                    double sa = ss[i], sb = ss[ixj];
                    int ia = ii[i], ib = ii[ixj];
                    const bool up = ((i & ksz) != 0);
                    const bool agtb = (sa > sb) || (sa == sb && ia < ib);
                    if (agtb == up) {
                        ss[i] = sb; ss[ixj] = sa;
                        ii[i] = ib; ii[ixj] = ia;
                        const int pa = pp[i]; pp[i] = pp[ixj]; pp[ixj] = pa;
                    }
                }
            }
            __syncthreads();
        }
    }

    for (int q = t; q < KQ; q += 512) {
        const double x = ss[q];
        const int idx = ii[q];
        out_scores[bb * KQ + q] = (float)(1.0 / (1.0 + exp(-x)));
        out_idx_f[bb * KQ + q] = (float)idx;
        ws_idx[bb * KQ + q] = idx;
        ws_pos[bb * KQ + q] = pp[q];
    }
}

// -------- Kernel 5: gather top-k memory rows, project, gather ref_points --------
__global__ __launch_bounds__(256) void gather_proj_kernel(
    const float* __restrict__ s3, const float* __restrict__ s4, const float* __restrict__ s5,
    const float* __restrict__ w_proj, const float* __restrict__ b_proj,
    const int* __restrict__ ws_idx, const int* __restrict__ ws_pos,
    const float* __restrict__ cand_mem, int use_cmem,
    const float* __restrict__ out_sboxes,
    float* __restrict__ out_tgt, float* __restrict__ out_ref)
{
    __shared__ float memQ[20][CDIM];
    __shared__ int qidx[20];
    __shared__ int qpos[20];
    const int t = threadIdx.x;
    const int bb = blockIdx.x / 15;
    const int tile = blockIdx.x % 15;
    const int q0 = tile * 20;

    if (t < 20) {
        qidx[t] = ws_idx[bb * KQ + q0 + t];
        qpos[t] = ws_pos[bb * KQ + q0 + t];
    }
    __syncthreads();

    if (use_cmem) {
        #pragma unroll 4
        for (int q = 0; q < 20; q++)
            memQ[q][t] = cand_mem[((size_t)bb * CANDMAX + qpos[q]) * CDIM + t];
    } else {
        #pragma unroll 4
        for (int q = 0; q < 20; q++) {
            const int n = qidx[q];
            const float* src; int nloc, lsz;
            locate_level(n, bb, s3, s4, s5, src, nloc, lsz);
            memQ[q][t] = src[(size_t)t * lsz + nloc];
        }
    }
    __syncthreads();

    const int j = t;
    float acc[20];
    #pragma unroll
    for (int q = 0; q < 20; q++) acc[q] = b_proj[j];
    for (int k = 0; k < CDIM; k++) {
        const float w = w_proj[(size_t)k * CDIM + j];
        #pragma unroll
        for (int q = 0; q < 20; q++) acc[q] = fmaf(memQ[q][k], w, acc[q]);
    }
    #pragma unroll
    for (int q = 0; q < 20; q++)
        out_tgt[(size_t)(bb * KQ + q0 + q) * CDIM + j] = acc[q];

    if (t < 80) {
        const int q = t >> 2, c = t & 3;
        const int n = qidx[q];
        out_ref[(size_t)(bb * KQ + q0 + q) * 4 + c] =
            out_sboxes[(size_t)(bb * NTOK + n) * 4 + c];
    }
}

extern "C" void kernel_launch(void* const* d_in, const int* in_sizes, int n_in,
                              void* d_out, int out_size, void* d_ws, size_t ws_size,
                              hipStream_t stream) {
    const float* s3      = (const float*)d_in[0];
    const float* s4      = (const float*)d_in[1];
    const float* s5      = (const float*)d_in[2];
    const float* w_score = (const float*)d_in[3];
    const float* b_score = (const float*)d_in[4];
    const float* w1      = (const float*)d_in[5];
    const float* b1      = (const float*)d_in[6];
    const float* w2      = (const float*)d_in[7];
    const float* b2      = (const float*)d_in[8];
    const float* w3      = (const float*)d_in[9];
    const float* b3      = (const float*)d_in[10];
    const float* w_proj  = (const float*)d_in[11];
    const float* b_proj  = (const float*)d_in[12];

    float* out = (float*)d_out;
    float* out_tgt    = out;                 // 16*300*256
    float* out_ref    = out + 1228800;       // 16*300*4
    float* out_logits = out + 1248000;       // 16*21504*80
    float* out_sboxes = out + 28773120;      // 16*21504*4
    float* out_idx    = out + 30149376;      // 16*300 (as float)
    float* out_scores = out + 30154176;      // 16*300

    char* ws = (char*)d_ws;
    float*        ws_scores  = (float*)(ws + 0);              // 1,376,256
    double*       cand_score = (double*)(ws + 1376256);       //   131,072
    int*          cand_idx   = (int*)(ws + 1507328);          //    65,536
    unsigned int* cand_cnt   = (unsigned int*)(ws + 1572864); //       256
    int*          ws_idx     = (int*)(ws + 1573120);          //    19,456
    int*          ws_pos     = (int*)(ws + 1592576);          //    19,456
    ushort_t*     w1T        = (ushort_t*)(ws + 1612032);     //   131,072
    ushort_t*     w2T        = (ushort_t*)(ws + 1743104);     //   131,072
    ushort_t*     wsT        = (ushort_t*)(ws + 1874176);     //    49,152
    float*        cand_mem   = (float*)(ws + 1923328);        // 16,777,216
    const int use_cmem = (ws_size >= (size_t)1923328 + 16777216) ? 1 : 0;

    // select scratch ALIASES w1T/w2T: weights are consumed by enc before select.
    unsigned int* hist    = (unsigned int*)(ws + 1612032);    // 16*2048*4 = 131,072
    unsigned int* tkeyArr = (unsigned int*)(ws + 1743104);    // 64

    prep_weights<<<608, 256, 0, stream>>>(w1, w2, w_score, w1T, w2T, wsT);

    enc_mfma_kernel<<<BATCH * 336, 256, 0, stream>>>(
        s3, s4, s5, w1T, w2T, wsT, b_score, b1, b2, w3, b3,
        out_logits, out_sboxes, ws_scores);

    zero_sel<<<32, 256, 0, stream>>>(hist, cand_cnt);
    hist_sel<<<256, 256, 0, stream>>>(ws_scores, hist);
    scan_sel<<<BATCH, 256, 0, stream>>>(hist, tkeyArr);
    collect_sel<<<256, 256, 0, stream>>>(ws_scores, tkeyArr, cand_idx, cand_cnt);

    rescore_kernel<<<BATCH * CANDMAX, 256, 0, stream>>>(
        s3, s4, s5, w_score, b_score, cand_idx, cand_cnt,
        cand_score, cand_mem, use_cmem);

    fsort_kernel<<<BATCH, 512, 0, stream>>>(
        cand_score, cand_idx, cand_cnt, out_idx, out_scores, ws_idx, ws_pos);

    gather_proj_kernel<<<BATCH * 15, 256, 0, stream>>>(
        s3, s4, s5, w_proj, b_proj, ws_idx, ws_pos, cand_mem, use_cmem,
        out_sboxes, out_tgt, out_ref);
}

// Round 9
// 1007.811 us; speedup vs baseline: 1.7389x; 1.7389x over previous
//
#include <hip/hip_runtime.h>
#include <math.h>

#define BATCH 16
#define CDIM 256
#define NCLS 80
#define N3 16384
#define N4 4096
#define N5 1024
#define NTOK 21504
#define KQ 300
#define KSEL 512
#define CANDMAX 1024
#define HBIN 2048
#define KMIN 0x3E800000u   // fp32 bits of 0.25

typedef __attribute__((ext_vector_type(8))) short short8;
typedef __attribute__((ext_vector_type(4))) float floatx4;
typedef unsigned short ushort_t;

// ldsA address (u16 units): [tok][264], 16B-chunk XOR-swizzled by tok&7.
#define LA(tok, k) (((tok) * 264) + (((((k) >> 3) ^ ((tok) & 7)) << 3) | ((k) & 7)))

__device__ __forceinline__ float sigmoidf_(float x) {
    return 1.0f / (1.0f + __expf(-x));
}

__device__ __forceinline__ ushort_t f2bf(float f) {   // RNE f32->bf16
    unsigned int x = __float_as_uint(f);
    unsigned int r = (x + 0x7FFFu + ((x >> 16) & 1u)) >> 16;
    return (ushort_t)r;
}

__device__ __forceinline__ void gload16(const void* g, void* l) {
    __builtin_amdgcn_global_load_lds(
        (const __attribute__((address_space(1))) unsigned int*)g,
        (__attribute__((address_space(3))) unsigned int*)l,
        16, 0, 0);
}

__device__ __forceinline__ void locate_level(
    int n, int bb,
    const float* __restrict__ s3, const float* __restrict__ s4, const float* __restrict__ s5,
    const float*& src, int& nloc, int& lsz)
{
    if (n < N3)           { src = s3 + (size_t)bb * CDIM * N3; nloc = n;           lsz = N3; }
    else if (n < N3 + N4) { src = s4 + (size_t)bb * CDIM * N4; nloc = n - N3;      lsz = N4; }
    else                  { src = s5 + (size_t)bb * CDIM * N5; nloc = n - N3 - N4; lsz = N5; }
}

// -------- Kernel 0: transpose+cast weights to bf16 W^T[col][k], PRE-SWIZZLED --------
__global__ __launch_bounds__(256) void prep_weights(
    const float* __restrict__ w1, const float* __restrict__ w2,
    const float* __restrict__ w_score,
    ushort_t* __restrict__ w1T, ushort_t* __restrict__ w2T, ushort_t* __restrict__ wsT)
{
    const int k = threadIdx.x;
    const int c = blockIdx.x;
    const int klo = k & 7;
    if (c < 256) {
        const size_t d = (size_t)c * 256 + ((((k >> 3) ^ (c & 7)) << 3) | klo);
        w1T[d] = f2bf(w1[k * 256 + c]);
    } else if (c < 512) {
        const int c2 = c - 256;
        const size_t d = (size_t)c2 * 256 + ((((k >> 3) ^ (c2 & 7)) << 3) | klo);
        w2T[d] = f2bf(w2[k * 256 + c2]);
    } else {
        const int c2 = c - 512;
        const size_t d = (size_t)c2 * 256 + ((((k >> 3) ^ (c2 & 7)) << 3) | klo);
        wsT[d] = (c2 < NCLS) ? f2bf(w_score[k * NCLS + c2]) : (ushort_t)0;
    }
}

// -------- Kernel 1: fused encoder head, counted-vmcnt pipeline, STATIC reg indexing --------
// grid: BATCH*336 blocks (64 tokens), 256 threads = 4 waves.
// 19 colblocks x 2 half-phases; 8KB weight half-chunks in wbufL[3] (rotating).
// Per phase: 4 MFMAs (static af indices) -> epilogue -> issue stage s+2 LAST ->
// "s_waitcnt vmcnt(2); s_barrier" (phase s+1's DMA drained, s+2's 2 loads in
// flight across the barrier). Drain to 0 only in the final two phases.
__global__ __launch_bounds__(256, 2) void enc_mfma_kernel(
    const float* __restrict__ s3, const float* __restrict__ s4, const float* __restrict__ s5,
    const ushort_t* __restrict__ w1T, const ushort_t* __restrict__ w2T,
    const ushort_t* __restrict__ wsT,
    const float* __restrict__ b_score, const float* __restrict__ b1,
    const float* __restrict__ b2,
    const float* __restrict__ w3, const float* __restrict__ b3,
    float* __restrict__ out_logits, float* __restrict__ out_sboxes,
    float* __restrict__ ws_scores)
{
    __shared__ __align__(16) ushort_t ldsA[64 * 264];       // 33792 B: memB then h1
    __shared__ __align__(16) ushort_t wbufL[3][32 * 128];   // 3 x 8192 B (linear DMA dest)
    __shared__ float bsc_s[80];
    __shared__ float b1_s[256];
    __shared__ float b2_s[256];
    __shared__ __align__(16) float w3_s[256 * 4];
    __shared__ float smax_s[2][64];
    __shared__ __align__(16) float boxp[2][64][4];

    const int t = threadIdx.x;
    const int lane = t & 63;
    const int w = t >> 6;
    const int tw = w & 1;                 // token half: tiles {32tw, 32tw+16}
    const int cw = w >> 1;                // col half within each 32-col chunk
    const int ml = lane & 15;
    const int quad = lane >> 4;
    const int kq = quad * 8;
    const int m8 = ml & 7;

    const int bb = blockIdx.x / 336;
    const int tile_ = blockIdx.x % 336;
    const int T0 = tile_ * 64;

    // stage one 32col x 128k half-chunk (8 KB): 2 gload16/thread.
    // Global: col row 512B, k-half h = swizzled-chunk bytes [h*256, h*256+256).
    // LDS: col*256B + chunk_in_half*16B (matches read-side addressing below).
    auto stage_half = [&](const ushort_t* wg, int h, int dbuf) {
        const char* gb = (const char*)wg + h * 256;
        char* l = (char*)&wbufL[dbuf][0];
        #pragma unroll
        for (int ii = 0; ii < 2; ++ii) {
            const int u = t + 256 * ii;                  // 0..511
            gload16(gb + (u >> 4) * 512 + (u & 15) * 16, l + u * 16);
        }
    };

    // helper: weight pointer for pipeline step s (colblock s>>1, half s&1)
    auto wsrc = [&](int s) -> const ushort_t* {
        const int jc = s >> 1;
        return (jc < 3)  ? (wsT + (size_t)jc * 8192)
             : (jc < 11) ? (w1T + (size_t)(jc - 3) * 8192)
                         : (w2T + (size_t)(jc - 11) * 8192);
    };

    stage_half(wsT, 0, 0);                // step 0 DMA in flight during staging

    if (t < 80) bsc_s[t] = b_score[t];
    b1_s[t] = b1[t];
    b2_s[t] = b2[t];
    *(float4*)&w3_s[t * 4] = *(const float4*)(w3 + t * 4);

    const float* src; int nloc, lsz;
    locate_level(T0, bb, s3, s4, s5, src, nloc, lsz);

    // ---- stage memory tile TRANSPOSED: [k][tok] global -> [tok][k] LDS (swizzled) ----
    {
        const int tokq = t & 15;          // owns toks 4*tokq .. +3
        const int kg = t >> 4;            // 16 k-groups of 8
        #pragma unroll
        for (int p = 0; p < 2; ++p) {
            const int kbase = 8 * kg + 128 * p;
            float4 v[8];
            #pragma unroll
            for (int j = 0; j < 8; ++j)
                v[j] = *(const float4*)(src + (size_t)(kbase + j) * lsz + nloc + 4 * tokq);
            #pragma unroll
            for (int r = 0; r < 4; ++r) {
                short8 a;
                #pragma unroll
                for (int j = 0; j < 8; ++j)
                    a[j] = (short)f2bf(((const float*)&v[j])[r]);
                *(short8*)&ldsA[LA(4 * tokq + r, kbase)] = a;
            }
        }
    }

    __builtin_amdgcn_sched_barrier(0);
    stage_half(wsT, 1, 1);                // step 1 DMA (issued late: newest 2 ops)
    // drain step 0's DMA + everything older (features), keep step 1 in flight
    asm volatile("s_waitcnt vmcnt(2) lgkmcnt(0)\ns_barrier" ::: "memory");

    // ---- A1 fragments: 16 x ds_read_b128 (row=tok=32tw+16tl+ml, k=32f+kq..+8) ----
    short8 af[2][8];
    #pragma unroll
    for (int tl = 0; tl < 2; ++tl) {
        const int tok = 32 * tw + 16 * tl + ml;
        #pragma unroll
        for (int f = 0; f < 8; ++f)
            af[tl][f] = *(const short8*)&ldsA[LA(tok, 32 * f + kq)];
    }

    const int gtok0 = bb * NTOK + T0;

    float smaxr[2][4];
    #pragma unroll
    for (int tl = 0; tl < 2; ++tl)
        #pragma unroll
        for (int r = 0; r < 4; ++r) smaxr[tl][r] = -1e30f;

    float psum[2][4][4];
    #pragma unroll
    for (int tl = 0; tl < 2; ++tl)
        #pragma unroll
        for (int r = 0; r < 4; ++r)
            #pragma unroll
            for (int c = 0; c < 4; ++c) psum[tl][r][c] = 0.f;

    const int brow = (16 * cw + ml) * 128;   // col row within an 8KB half-chunk
    int bufc = 0;                             // buffer holding current phase's data

    for (int cb = 0; cb < 19; ++cb) {
        // A2 fragments from h1 (complete as of barrier ending cb==10's h=1 phase)
        if (cb == 11) {
            #pragma unroll
            for (int tl = 0; tl < 2; ++tl) {
                const int tok = 32 * tw + 16 * tl + ml;
                #pragma unroll
                for (int f = 0; f < 8; ++f)
                    af[tl][f] = *(const short8*)&ldsA[LA(tok, 32 * f + kq)];
            }
        }

        floatx4 acc0 = {0.f, 0.f, 0.f, 0.f};
        floatx4 acc1 = {0.f, 0.f, 0.f, 0.f};

        // ======== phase h=0: k=[0,128), buffer bufc ========
        {
            const ushort_t* wb = &wbufL[bufc][0];
            __builtin_amdgcn_s_setprio(1);
            #pragma unroll
            for (int f2 = 0; f2 < 4; ++f2) {
                const short8 bf = *(const short8*)&wb[brow + (((4 * f2 + quad) ^ m8) << 3)];
                acc0 = __builtin_amdgcn_mfma_f32_16x16x32_bf16(af[0][f2], bf, acc0, 0, 0, 0);
                acc1 = __builtin_amdgcn_mfma_f32_16x16x32_bf16(af[1][f2], bf, acc1, 0, 0, 0);
            }
            __builtin_amdgcn_s_setprio(0);

            __builtin_amdgcn_sched_barrier(0);
            const int s = 2 * cb + 2;
            if (s < 38) {
                stage_half(wsrc(s), s & 1, (bufc + 2) % 3);
                asm volatile("s_waitcnt vmcnt(2) lgkmcnt(0)\ns_barrier" ::: "memory");
            } else {
                asm volatile("s_waitcnt vmcnt(0) lgkmcnt(0)\ns_barrier" ::: "memory");
            }
            bufc = (bufc == 2) ? 0 : bufc + 1;
        }

        // ======== phase h=1: k=[128,256), buffer bufc ========
        {
            const ushort_t* wb = &wbufL[bufc][0];
            __builtin_amdgcn_s_setprio(1);
            #pragma unroll
            for (int f2 = 0; f2 < 4; ++f2) {
                const short8 bf = *(const short8*)&wb[brow + (((4 * f2 + quad) ^ m8) << 3)];
                acc0 = __builtin_amdgcn_mfma_f32_16x16x32_bf16(af[0][4 + f2], bf, acc0, 0, 0, 0);
                acc1 = __builtin_amdgcn_mfma_f32_16x16x32_bf16(af[1][4 + f2], bf, acc1, 0, 0, 0);
            }
            __builtin_amdgcn_s_setprio(0);

            // ---- epilogue for colblock cb (acc now complete over k=256) ----
            if (cb < 3) {
                const int col = 32 * cb + 16 * cw + ml;
                if (col < NCLS) {         // wave-uniform per (cb,cw)
                    const float bias = bsc_s[col];
                    #pragma unroll
                    for (int tl = 0; tl < 2; ++tl)
                        #pragma unroll
                        for (int r = 0; r < 4; ++r) {
                            const float v = (tl ? acc1[r] : acc0[r]) + bias;
                            const int ltok = 32 * tw + 16 * tl + 4 * quad + r;
                            out_logits[(size_t)(gtok0 + ltok) * NCLS + col] = v;
                            smaxr[tl][r] = fmaxf(smaxr[tl][r], v);
                        }
                }
                if (cb == 2) {            // GEMM1 done: reduce over 16 col-lanes
                    #pragma unroll
                    for (int tl = 0; tl < 2; ++tl)
                        #pragma unroll
                        for (int r = 0; r < 4; ++r) {
                            float m = smaxr[tl][r];
                            m = fmaxf(m, __shfl_xor(m, 1));
                            m = fmaxf(m, __shfl_xor(m, 2));
                            m = fmaxf(m, __shfl_xor(m, 4));
                            m = fmaxf(m, __shfl_xor(m, 8));
                            if (ml == 0)
                                smax_s[cw][32 * tw + 16 * tl + 4 * quad + r] = m;
                        }
                }
            } else if (cb < 11) {
                // GEMM2: h1 = relu(.) -> ldsA (A1 already in regs)
                const int col = 32 * (cb - 3) + 16 * cw + ml;
                const float bias = b1_s[col];
                #pragma unroll
                for (int tl = 0; tl < 2; ++tl)
                    #pragma unroll
                    for (int r = 0; r < 4; ++r) {
                        const float v = fmaxf((tl ? acc1[r] : acc0[r]) + bias, 0.f);
                        const int ltok = 32 * tw + 16 * tl + 4 * quad + r;
                        ldsA[LA(ltok, col)] = f2bf(v);
                    }
            } else {
                // GEMM3: h2 = relu(.); boxes folded in-register
                const int col = 32 * (cb - 11) + 16 * cw + ml;
                const float bias = b2_s[col];
                const float4 w3v = *(const float4*)&w3_s[col * 4];
                #pragma unroll
                for (int tl = 0; tl < 2; ++tl)
                    #pragma unroll
                    for (int r = 0; r < 4; ++r) {
                        const float v = fmaxf((tl ? acc1[r] : acc0[r]) + bias, 0.f);
                        psum[tl][r][0] = fmaf(v, w3v.x, psum[tl][r][0]);
                        psum[tl][r][1] = fmaf(v, w3v.y, psum[tl][r][1]);
                        psum[tl][r][2] = fmaf(v, w3v.z, psum[tl][r][2]);
                        psum[tl][r][3] = fmaf(v, w3v.w, psum[tl][r][3]);
                    }
            }

            __builtin_amdgcn_sched_barrier(0);
            const int s = 2 * cb + 3;
            if (s < 38) {
                stage_half(wsrc(s), s & 1, (bufc + 2) % 3);
                asm volatile("s_waitcnt vmcnt(2) lgkmcnt(0)\ns_barrier" ::: "memory");
            } else {
                asm volatile("s_waitcnt vmcnt(0) lgkmcnt(0)\ns_barrier" ::: "memory");
            }
            bufc = (bufc == 2) ? 0 : bufc + 1;
        }
    }

    // ---- boxes: reduce psum over 16 col-lanes, cross-wave (cw) combine via LDS ----
    #pragma unroll
    for (int tl = 0; tl < 2; ++tl)
        #pragma unroll
        for (int r = 0; r < 4; ++r) {
            float4 pv;
            float* pva = (float*)&pv;
            #pragma unroll
            for (int c = 0; c < 4; ++c) {
                float v = psum[tl][r][c];
                v += __shfl_xor(v, 1);
                v += __shfl_xor(v, 2);
                v += __shfl_xor(v, 4);
                v += __shfl_xor(v, 8);
                pva[c] = v;
            }
            if (ml == 0)
                *(float4*)&boxp[cw][32 * tw + 16 * tl + 4 * quad + r][0] = pv;
        }
    __syncthreads();

    if (t < 64)
        ws_scores[gtok0 + t] = sigmoidf_(fmaxf(smax_s[0][t], smax_s[1][t]));
    {
        const int tok = t >> 2, c = t & 3;
        const float bx = boxp[0][tok][c] + boxp[1][tok][c] + b3[c];
        out_sboxes[(size_t)(gtok0 + tok) * 4 + c] = sigmoidf_(bx);
    }
}

// -------- select stage A: zero hist + cand_cnt --------
__global__ __launch_bounds__(256) void zero_sel(
    unsigned int* __restrict__ hist, unsigned int* __restrict__ cand_cnt)
{
    const int idx = blockIdx.x * 256 + threadIdx.x;
    for (int i = idx; i < BATCH * HBIN; i += 32 * 256) hist[i] = 0u;
    if (idx < BATCH) cand_cnt[idx] = 0u;
}

// -------- select stage B: 256-block histogram over 2048 value-bins of [0.25,1) --------
__global__ __launch_bounds__(256) void hist_sel(
    const float* __restrict__ scores, unsigned int* __restrict__ hist)
{
    __shared__ unsigned int lhist[HBIN];
    const int t = threadIdx.x;
    const int bb = blockIdx.x >> 4;
    const int slice = blockIdx.x & 15;
    const float* s = scores + bb * NTOK;
    #pragma unroll
    for (int j = 0; j < HBIN / 256; ++j) lhist[t + 256 * j] = 0u;
    __syncthreads();

    const int base = slice * (NTOK / 16);
    for (int n = base + t; n < base + NTOK / 16; n += 256) {
        const unsigned int key = __float_as_uint(s[n]);
        int b;
        if (key < KMIN) b = 0;
        else {
            unsigned int d = (key - KMIN) >> 13;
            b = (d > (unsigned int)(HBIN - 1)) ? (HBIN - 1) : (int)d;
        }
        atomicAdd(&lhist[b], 1u);
    }
    __syncthreads();
    #pragma unroll
    for (int j = 0; j < HBIN / 256; ++j) {
        const unsigned int v = lhist[t + 256 * j];
        if (v) atomicAdd(&hist[bb * HBIN + t + 256 * j], v);
    }
}

// -------- select stage C: scan hist, pick threshold key (suffix >= KSEL) --------
__global__ __launch_bounds__(256) void scan_sel(
    const unsigned int* __restrict__ hist, unsigned int* __restrict__ tkeyArr)
{
    __shared__ unsigned int part[256];
    const int bb = blockIdx.x;
    const int t = threadIdx.x;
    unsigned int s = 0;
    #pragma unroll
    for (int j = 0; j < 8; ++j) s += hist[bb * HBIN + t * 8 + j];
    part[t] = s;
    __syncthreads();
    if (t == 0) {
        int acc = 0, g = 255;
        for (; g >= 0; --g) {
            if (acc + (int)part[g] >= KSEL) break;
            acc += (int)part[g];
        }
        unsigned int key;
        if (g < 0) {
            key = 1u;                      // degenerate: take all positive scores
        } else {
            int b = 8 * g + 7;
            for (; b > 8 * g; --b) {
                acc += (int)hist[bb * HBIN + b];
                if (acc >= KSEL) break;
            }
            if (acc < KSEL) { acc += (int)hist[bb * HBIN + 8 * g]; b = 8 * g; }
            key = (b == 0) ? 1u : (KMIN + ((unsigned int)b << 13));
        }
        tkeyArr[bb] = key;
    }
}

// -------- select stage D: parallel ballot-collect of all tokens >= Tkey --------
__global__ __launch_bounds__(256) void collect_sel(
    const float* __restrict__ scores, const unsigned int* __restrict__ tkeyArr,
    int* __restrict__ cand_idx, unsigned int* __restrict__ cand_cnt)
{
    const int t = threadIdx.x;
    const int lane = t & 63;
    const int bb = blockIdx.x >> 4;
    const int slice = blockIdx.x & 15;
    const float* s = scores + bb * NTOK;
    const unsigned int Tkey = tkeyArr[bb];

    const int base = slice * (NTOK / 16);
    for (int n = base + t; n < base + NTOK / 16; n += 256) {
        const unsigned int key = __float_as_uint(s[n]);
        const bool pred = (key >= Tkey);
        const unsigned long long m = __ballot(pred);
        if (m) {
            const int leader = __builtin_ctzll(m);
            unsigned int bpos = 0;
            if (lane == leader)
                bpos = atomicAdd(&cand_cnt[bb], (unsigned int)__popcll(m));
            bpos = (unsigned int)__shfl((int)bpos, leader);
            if (pred) {
                const unsigned int pos =
                    bpos + (unsigned int)__popcll(m & ((1ull << lane) - 1ull));
                if (pos < CANDMAX) cand_idx[bb * CANDMAX + pos] = n;
            }
        }
    }
}

// -------- Kernel 3: f64 exact rescore, one block per candidate --------
__global__ __launch_bounds__(256) void rescore_kernel(
    const float* __restrict__ s3, const float* __restrict__ s4, const float* __restrict__ s5,
    const float* __restrict__ w_score, const float* __restrict__ b_score,
    const int* __restrict__ cand_idx, const unsigned int* __restrict__ cand_cnt,
    double* __restrict__ cand_score, float* __restrict__ cand_mem, int use_cmem)
{
    __shared__ float m_s[CDIM];
    __shared__ double part[256];

    const int t = threadIdx.x;
    const int bb = blockIdx.x / CANDMAX;
    const int cpos = blockIdx.x % CANDMAX;
    if ((unsigned int)cpos >= cand_cnt[bb]) return;

    const int n = cand_idx[bb * CANDMAX + cpos];
    const float* src; int nloc, lsz;
    locate_level(n, bb, s3, s4, s5, src, nloc, lsz);
    m_s[t] = src[(size_t)t * lsz + nloc];
    __syncthreads();

    if (use_cmem)
        cand_mem[((size_t)bb * CANDMAX + cpos) * CDIM + t] = m_s[t];

    const int ks = t >> 7;
    const int c = t & 127;
    double acc = 0.0;
    if (c < NCLS) {
        if (ks == 0) acc = (double)b_score[c];
        const int k0 = 128 * ks;
        for (int k = k0; k < k0 + 128; ++k)
            acc += (double)m_s[k] * (double)w_score[k * NCLS + c];
    }
    part[t] = acc;
    __syncthreads();

    if (t < 128) {
        double tot = (t < NCLS) ? (part[t] + part[t + 128]) : -1.0e300;
        part[t] = tot;
    }
    __syncthreads();

    if (t < 64) {
        double v = fmax(part[t], part[t + 64]);
        v = fmax(v, __shfl_xor(v, 1));
        v = fmax(v, __shfl_xor(v, 2));
        v = fmax(v, __shfl_xor(v, 4));
        v = fmax(v, __shfl_xor(v, 8));
        v = fmax(v, __shfl_xor(v, 16));
        v = fmax(v, __shfl_xor(v, 32));
        if (t == 0) cand_score[bb * CANDMAX + cpos] = v;
    }
}

// -------- Kernel 4: exact sort of candidates, emit top-300 (+cand position) --------
__global__ __launch_bounds__(512) void fsort_kernel(
    const double* __restrict__ cand_score, const int* __restrict__ cand_idx,
    const unsigned int* __restrict__ cand_cnt,
    float* __restrict__ out_idx_f, float* __restrict__ out_scores,
    int* __restrict__ ws_idx, int* __restrict__ ws_pos)
{
    __shared__ double ss[CANDMAX];
    __shared__ int    ii[CANDMAX];
    __shared__ int    pp[CANDMAX];
    const int bb = blockIdx.x;
    const int t = threadIdx.x;
    const unsigned int cnt = cand_cnt[bb];

    for (int i = t; i < CANDMAX; i += 512) {
        if ((unsigned int)i < cnt) {
            ss[i] = cand_score[bb * CANDMAX + i];
            ii[i] = cand_idx[bb * CANDMAX + i];
        } else {
            ss[i] = -1.0e300;
            ii[i] = 0x7FFFFFFF;
        }
        pp[i] = i;
    }
    __syncthreads();

    for (int ksz = 2; ksz <= CANDMAX; ksz <<= 1) {
        for (int j = ksz >> 1; j > 0; j >>= 1) {
            #pragma unroll
            for (int p = 0; p < CANDMAX / 512; p++) {
                const int i = p * 512 + t;
                const int ixj = i ^ j;
                if (ixj > i) {
                    double sa = ss[i], sb = ss[ixj];
                    int ia = ii[i], ib = ii[ixj];
                    const bool up = ((i & ksz) != 0);
                    const bool agtb = (sa > sb) || (sa == sb && ia < ib);
                    if (agtb == up) {
                        ss[i] = sb; ss[ixj] = sa;
                        ii[i] = ib; ii[ixj] = ia;
                        const int pa = pp[i]; pp[i] = pp[ixj]; pp[ixj] = pa;
                    }
                }
            }
            __syncthreads();
        }
    }

    for (int q = t; q < KQ; q += 512) {
        const double x = ss[q];
        const int idx = ii[q];
        out_scores[bb * KQ + q] = (float)(1.0 / (1.0 + exp(-x)));
        out_idx_f[bb * KQ + q] = (float)idx;
        ws_idx[bb * KQ + q] = idx;
        ws_pos[bb * KQ + q] = pp[q];
    }
}

// -------- Kernel 5: gather top-k memory rows, project, gather ref_points --------
__global__ __launch_bounds__(256) void gather_proj_kernel(
    const float* __restrict__ s3, const float* __restrict__ s4, const float* __restrict__ s5,
    const float* __restrict__ w_proj, const float* __restrict__ b_proj,
    const int* __restrict__ ws_idx, const int* __restrict__ ws_pos,
    const float* __restrict__ cand_mem, int use_cmem,
    const float* __restrict__ out_sboxes,
    float* __restrict__ out_tgt, float* __restrict__ out_ref)
{
    __shared__ float memQ[20][CDIM];
    __shared__ int qidx[20];
    __shared__ int qpos[20];
    const int t = threadIdx.x;
    const int bb = blockIdx.x / 15;
    const int tile = blockIdx.x % 15;
    const int q0 = tile * 20;

    if (t < 20) {
        qidx[t] = ws_idx[bb * KQ + q0 + t];
        qpos[t] = ws_pos[bb * KQ + q0 + t];
    }
    __syncthreads();

    if (use_cmem) {
        #pragma unroll 4
        for (int q = 0; q < 20; q++)
            memQ[q][t] = cand_mem[((size_t)bb * CANDMAX + qpos[q]) * CDIM + t];
    } else {
        #pragma unroll 4
        for (int q = 0; q < 20; q++) {
            const int n = qidx[q];
            const float* src; int nloc, lsz;
            locate_level(n, bb, s3, s4, s5, src, nloc, lsz);
            memQ[q][t] = src[(size_t)t * lsz + nloc];
        }
    }
    __syncthreads();

    const int j = t;
    float acc[20];
    #pragma unroll
    for (int q = 0; q < 20; q++) acc[q] = b_proj[j];
    for (int k = 0; k < CDIM; k++) {
        const float w = w_proj[(size_t)k * CDIM + j];
        #pragma unroll
        for (int q = 0; q < 20; q++) acc[q] = fmaf(memQ[q][k], w, acc[q]);
    }
    #pragma unroll
    for (int q = 0; q < 20; q++)
        out_tgt[(size_t)(bb * KQ + q0 + q) * CDIM + j] = acc[q];

    if (t < 80) {
        const int q = t >> 2, c = t & 3;
        const int n = qidx[q];
        out_ref[(size_t)(bb * KQ + q0 + q) * 4 + c] =
            out_sboxes[(size_t)(bb * NTOK + n) * 4 + c];
    }
}

extern "C" void kernel_launch(void* const* d_in, const int* in_sizes, int n_in,
                              void* d_out, int out_size, void* d_ws, size_t ws_size,
                              hipStream_t stream) {
    const float* s3      = (const float*)d_in[0];
    const float* s4      = (const float*)d_in[1];
    const float* s5      = (const float*)d_in[2];
    const float* w_score = (const float*)d_in[3];
    const float* b_score = (const float*)d_in[4];
    const float* w1      = (const float*)d_in[5];
    const float* b1      = (const float*)d_in[6];
    const float* w2      = (const float*)d_in[7];
    const float* b2      = (const float*)d_in[8];
    const float* w3      = (const float*)d_in[9];
    const float* b3      = (const float*)d_in[10];
    const float* w_proj  = (const float*)d_in[11];
    const float* b_proj  = (const float*)d_in[12];

    float* out = (float*)d_out;
    float* out_tgt    = out;                 // 16*300*256
    float* out_ref    = out + 1228800;       // 16*300*4
    float* out_logits = out + 1248000;       // 16*21504*80
    float* out_sboxes = out + 28773120;      // 16*21504*4
    float* out_idx    = out + 30149376;      // 16*300 (as float)
    float* out_scores = out + 30154176;      // 16*300

    char* ws = (char*)d_ws;
    float*        ws_scores  = (float*)(ws + 0);              // 1,376,256
    double*       cand_score = (double*)(ws + 1376256);       //   131,072
    int*          cand_idx   = (int*)(ws + 1507328);          //    65,536
    unsigned int* cand_cnt   = (unsigned int*)(ws + 1572864); //       256
    int*          ws_idx     = (int*)(ws + 1573120);          //    19,456
    int*          ws_pos     = (int*)(ws + 1592576);          //    19,456
    ushort_t*     w1T        = (ushort_t*)(ws + 1612032);     //   131,072
    ushort_t*     w2T        = (ushort_t*)(ws + 1743104);     //   131,072
    ushort_t*     wsT        = (ushort_t*)(ws + 1874176);     //    49,152
    float*        cand_mem   = (float*)(ws + 1923328);        // 16,777,216
    const int use_cmem = (ws_size >= (size_t)1923328 + 16777216) ? 1 : 0;

    // select scratch ALIASES w1T/w2T: weights are consumed by enc before select.
    unsigned int* hist    = (unsigned int*)(ws + 1612032);    // 16*2048*4 = 131,072
    unsigned int* tkeyArr = (unsigned int*)(ws + 1743104);    // 64

    prep_weights<<<608, 256, 0, stream>>>(w1, w2, w_score, w1T, w2T, wsT);

    enc_mfma_kernel<<<BATCH * 336, 256, 0, stream>>>(
        s3, s4, s5, w1T, w2T, wsT, b_score, b1, b2, w3, b3,
        out_logits, out_sboxes, ws_scores);

    zero_sel<<<32, 256, 0, stream>>>(hist, cand_cnt);
    hist_sel<<<256, 256, 0, stream>>>(ws_scores, hist);
    scan_sel<<<BATCH, 256, 0, stream>>>(hist, tkeyArr);
    collect_sel<<<256, 256, 0, stream>>>(ws_scores, tkeyArr, cand_idx, cand_cnt);

    rescore_kernel<<<BATCH * CANDMAX, 256, 0, stream>>>(
        s3, s4, s5, w_score, b_score, cand_idx, cand_cnt,
        cand_score, cand_mem, use_cmem);

    fsort_kernel<<<BATCH, 512, 0, stream>>>(
        cand_score, cand_idx, cand_cnt, out_idx, out_scores, ws_idx, ws_pos);

    gather_proj_kernel<<<BATCH * 15, 256, 0, stream>>>(
        s3, s4, s5, w_proj, b_proj, ws_idx, ws_pos, cand_mem, use_cmem,
        out_sboxes, out_tgt, out_ref);
}